// Round 10
// baseline (286.078 us; speedup 1.0000x reference)
//
#include <hip/hip_runtime.h>
#include <math.h>

#define N_NODES 50000
#define N_EDGES 800000
#define F_IN_DIM 128
#define HID 64
#define NG 512
#define NEG 0.2f
#define SLICE ((N_NODES + 7) / 8)   // 6250 nodes per XCD slice
#define EPB 2048                     // edges per 8-block group
#define CAP 64                       // bucket capacity per node

static __device__ __forceinline__ float wave_sum(float v) {
    for (int o = 32; o; o >>= 1) v += __shfl_xor(v, o, 64);
    return v;
}

// bf16 pack/unpack (RNE)
static __device__ __forceinline__ unsigned short f2bf(float f) {
    union { float f; unsigned u; } v; v.f = f;
    unsigned r = (v.u + 0x7FFF + ((v.u >> 16) & 1)) >> 16;
    return (unsigned short)r;
}
static __device__ __forceinline__ float bf2f(unsigned short b) {
    union { unsigned u; float f; } v; v.u = ((unsigned)b) << 16;
    return v.f;
}

// ---- single-pass bucket build (XCD-sliced by dst; real edges only) ----
// dst read by all 8 slice-replicas; src/ew only under the in-slice mask.
// slice-0 blocks accumulate mean(edge_weight); block 0 computes ce dots.
__global__ __launch_bounds__(256) void scatter_all_k(
        const int* __restrict__ ei, const float* __restrict__ ew,
        int* __restrict__ deg, unsigned* __restrict__ bucket,
        uint2* __restrict__ ovf, int* __restrict__ ovf_cnt,
        float* __restrict__ mean_acc,
        const float* __restrict__ We1, const float* __restrict__ ae1,
        const float* __restrict__ We2, const float* __restrict__ ae2,
        const float* __restrict__ We3, const float* __restrict__ ae3,
        float* __restrict__ ce) {
    int grp = blockIdx.x >> 3, slice = blockIdx.x & 7;
    int lo = slice * SLICE, hi = lo + SLICE;
    int base = grp * EPB;
    int lim = min(base + EPB, N_EDGES);
    float s = 0.f;
    for (int e = base + threadIdx.x; e < lim; e += 256) {
        int dst = ei[N_EDGES + e];
        if (slice == 0) s += ew[e];
        if (dst >= lo && dst < hi) {
            int src = ei[e];
            float w = ew[e];
            int pos = atomicAdd(&deg[dst], 1);
            unsigned entry = (unsigned)(src & 0xFFFF) | ((unsigned)f2bf(w) << 16);
            if (pos < CAP) bucket[(dst << 6) + pos] = entry;
            else { int op = atomicAdd(ovf_cnt, 1); ovf[op] = make_uint2((unsigned)dst, entry); }
        }
    }
    int lane = threadIdx.x & 63, wv = threadIdx.x >> 6;
    if (slice == 0) {
        s = wave_sum(s);
        __shared__ float tmp[4];
        if (lane == 0) tmp[wv] = s;
        __syncthreads();
        if (threadIdx.x == 0) atomicAdd(mean_acc, tmp[0] + tmp[1] + tmp[2] + tmp[3]);
    }
    if (blockIdx.x == 0 && wv >= 1) {
        const float* We = (wv == 1) ? We1 : (wv == 2) ? We2 : We3;
        const float* ae = (wv == 1) ? ae1 : (wv == 2) ? ae2 : ae3;
        float v = We[lane] * ae[lane];
        v = wave_sum(v);
        if (lane == 0) ce[wv - 1] = v;
    }
}

// ---- H = X @ W (register-tiled), H stored bf16, fused a_src/a_dst ----
__global__ __launch_bounds__(256) void gemm_att_k(
        const float* __restrict__ X, int F,
        const float* __restrict__ W,
        const float* __restrict__ as_, const float* __restrict__ ad_,
        unsigned short* __restrict__ H, float* __restrict__ Asrc,
        float* __restrict__ Adst) {
    extern __shared__ float smem[];
    float* Ws = smem;               // F*64 floats
    float* Xs = smem + F * HID;     // 64*17 floats
    const int tid = threadIdx.x;
    const int tx = tid & 15, ty = tid >> 4;
    const int rowBase = blockIdx.x * 64;

    {
        const float4* W4 = (const float4*)W;
        float4* Ws4 = (float4*)Ws;
        int n4 = (F * HID) >> 2;
        for (int i = tid; i < n4; i += 256) Ws4[i] = W4[i];
    }

    float4 acc0 = {0,0,0,0}, acc1 = {0,0,0,0}, acc2 = {0,0,0,0}, acc3 = {0,0,0,0};

    const int xrow = tid >> 2;
    const int xkq  = tid & 3;
    const int nkt = F >> 4;

    for (int kt = 0; kt < nkt; ++kt) {
        __syncthreads();
        int k0 = kt << 4;
        int grow = rowBase + xrow;
        float4 xv = {0,0,0,0};
        if (grow < N_NODES)
            xv = *(const float4*)(X + (size_t)grow * F + k0 + (xkq << 2));
        float* xd = Xs + xrow * 17 + (xkq << 2);
        xd[0] = xv.x; xd[1] = xv.y; xd[2] = xv.z; xd[3] = xv.w;
        __syncthreads();

        #pragma unroll
        for (int kk = 0; kk < 16; ++kk) {
            float4 b = *(const float4*)&Ws[(k0 + kk) * HID + (tx << 2)];
            float a0 = Xs[(ty * 4 + 0) * 17 + kk];
            float a1 = Xs[(ty * 4 + 1) * 17 + kk];
            float a2 = Xs[(ty * 4 + 2) * 17 + kk];
            float a3 = Xs[(ty * 4 + 3) * 17 + kk];
            acc0.x += a0 * b.x; acc0.y += a0 * b.y; acc0.z += a0 * b.z; acc0.w += a0 * b.w;
            acc1.x += a1 * b.x; acc1.y += a1 * b.y; acc1.z += a1 * b.z; acc1.w += a1 * b.w;
            acc2.x += a2 * b.x; acc2.y += a2 * b.y; acc2.z += a2 * b.z; acc2.w += a2 * b.w;
            acc3.x += a3 * b.x; acc3.y += a3 * b.y; acc3.z += a3 * b.z; acc3.w += a3 * b.w;
        }
    }

    float4 as4 = *(const float4*)(as_ + (tx << 2));
    float4 ad4 = *(const float4*)(ad_ + (tx << 2));
    float4 accs[4] = {acc0, acc1, acc2, acc3};
    #pragma unroll
    for (int i = 0; i < 4; ++i) {
        int row = rowBase + ty * 4 + i;
        if (row >= N_NODES) break;
        float4 a = accs[i];
        ushort4 hv;
        hv.x = f2bf(a.x); hv.y = f2bf(a.y); hv.z = f2bf(a.z); hv.w = f2bf(a.w);
        *(ushort4*)(H + (size_t)row * HID + (tx << 2)) = hv;
        float vs = a.x * as4.x + a.y * as4.y + a.z * as4.z + a.w * as4.w;
        float vd = a.x * ad4.x + a.y * ad4.y + a.z * ad4.z + a.w * ad4.w;
        #pragma unroll
        for (int o = 8; o; o >>= 1) { vs += __shfl_xor(vs, o, 64); vd += __shfl_xor(vd, o, 64); }
        if (tx == 0) { Asrc[row] = vs; Adst[row] = vd; }
    }
}

// ---- per-dst-node softmax + weighted gather (bucket layout, self-loop inline) ----
__global__ __launch_bounds__(256) void aggregate_k(
        const unsigned short* __restrict__ H, const int* __restrict__ degArr,
        const unsigned* __restrict__ bucket,
        const uint2* __restrict__ ovf, const int* __restrict__ ovf_cnt_p,
        const float* __restrict__ Asrc, const float* __restrict__ Adst,
        const float* __restrict__ ceArr, int ci,
        const float* __restrict__ mean_acc,
        const float* __restrict__ bias, float* __restrict__ Out,
        int do_relu) {
    __shared__ float lp[16][64];
    __shared__ int   ls[16][64];
    int wv = threadIdx.x >> 6, lane = threadIdx.x & 63;
    int qid = lane >> 4, qlane = lane & 15;
    int slot = wv * 4 + qid;
    int n = blockIdx.x * 16 + slot;
    if (n >= N_NODES) return;
    int deg = degArr[n];
    int start = n << 6;
    float c = ceArr[ci];
    float ad = Adst[n];
    float mv = mean_acc[0] * (1.0f / (float)N_EDGES);
    float4 acc = {0, 0, 0, 0};
    float denom;

    float a_self = Asrc[n] + ad + c * mv;
    a_self = (a_self > 0.f) ? a_self : NEG * a_self;
    float p_self = __expf(a_self);

    if (deg <= CAP) {
        float lsum = 0.f;
        #pragma unroll
        for (int t = 0; t < 4; ++t) {
            int j = qlane + (t << 4);
            float p = 0.f; int s = 0;
            if (j < deg) {
                unsigned e = bucket[start + j];
                s = e & 0xFFFF;
                float a = Asrc[s] + ad + c * bf2f((unsigned short)(e >> 16));
                a = (a > 0.f) ? a : NEG * a;
                p = __expf(a);
                lsum += p;
            }
            lp[slot][j] = p;
            ls[slot][j] = s;
        }
        if (qlane == 0) lsum += p_self;
        #pragma unroll
        for (int o = 1; o < 16; o <<= 1) lsum += __shfl_xor(lsum, o, 64);
        denom = lsum;
        __builtin_amdgcn_wave_barrier();
        int dpad = (deg + 7) & ~7;
        for (int j = 0; j < dpad; j += 8) {
            float4 p0 = *(float4*)&lp[slot][j];
            float4 p1 = *(float4*)&lp[slot][j + 4];
            int4 s0 = *(int4*)&ls[slot][j];
            int4 s1 = *(int4*)&ls[slot][j + 4];
            ushort4 r0 = *(const ushort4*)(H + (size_t)s0.x * HID + (qlane << 2));
            ushort4 r1 = *(const ushort4*)(H + (size_t)s0.y * HID + (qlane << 2));
            ushort4 r2 = *(const ushort4*)(H + (size_t)s0.z * HID + (qlane << 2));
            ushort4 r3 = *(const ushort4*)(H + (size_t)s0.w * HID + (qlane << 2));
            ushort4 r4 = *(const ushort4*)(H + (size_t)s1.x * HID + (qlane << 2));
            ushort4 r5 = *(const ushort4*)(H + (size_t)s1.y * HID + (qlane << 2));
            ushort4 r6 = *(const ushort4*)(H + (size_t)s1.z * HID + (qlane << 2));
            ushort4 r7 = *(const ushort4*)(H + (size_t)s1.w * HID + (qlane << 2));
            acc.x += p0.x*bf2f(r0.x) + p0.y*bf2f(r1.x) + p0.z*bf2f(r2.x) + p0.w*bf2f(r3.x)
                   + p1.x*bf2f(r4.x) + p1.y*bf2f(r5.x) + p1.z*bf2f(r6.x) + p1.w*bf2f(r7.x);
            acc.y += p0.x*bf2f(r0.y) + p0.y*bf2f(r1.y) + p0.z*bf2f(r2.y) + p0.w*bf2f(r3.y)
                   + p1.x*bf2f(r4.y) + p1.y*bf2f(r5.y) + p1.z*bf2f(r6.y) + p1.w*bf2f(r7.y);
            acc.z += p0.x*bf2f(r0.z) + p0.y*bf2f(r1.z) + p0.z*bf2f(r2.z) + p0.w*bf2f(r3.z)
                   + p1.x*bf2f(r4.z) + p1.y*bf2f(r5.z) + p1.z*bf2f(r6.z) + p1.w*bf2f(r7.z);
            acc.w += p0.x*bf2f(r0.w) + p0.y*bf2f(r1.w) + p0.z*bf2f(r2.w) + p0.w*bf2f(r3.w)
                   + p1.x*bf2f(r4.w) + p1.y*bf2f(r5.w) + p1.z*bf2f(r6.w) + p1.w*bf2f(r7.w);
        }
    } else {
        int novf = *ovf_cnt_p;
        float lsum = 0.f;
        #pragma unroll
        for (int t = 0; t < 4; ++t) {
            int j = qlane + (t << 4);
            unsigned e = bucket[start + j];
            int s = e & 0xFFFF;
            float a = Asrc[s] + ad + c * bf2f((unsigned short)(e >> 16));
            a = (a > 0.f) ? a : NEG * a;
            float p = __expf(a);
            lsum += p;
            lp[slot][j] = p;
            ls[slot][j] = s;
        }
        __builtin_amdgcn_wave_barrier();
        for (int j = 0; j < 64; j += 8) {
            float4 p0 = *(float4*)&lp[slot][j];
            float4 p1 = *(float4*)&lp[slot][j + 4];
            int4 s0 = *(int4*)&ls[slot][j];
            int4 s1 = *(int4*)&ls[slot][j + 4];
            ushort4 r0 = *(const ushort4*)(H + (size_t)s0.x * HID + (qlane << 2));
            ushort4 r1 = *(const ushort4*)(H + (size_t)s0.y * HID + (qlane << 2));
            ushort4 r2 = *(const ushort4*)(H + (size_t)s0.z * HID + (qlane << 2));
            ushort4 r3 = *(const ushort4*)(H + (size_t)s0.w * HID + (qlane << 2));
            ushort4 r4 = *(const ushort4*)(H + (size_t)s1.x * HID + (qlane << 2));
            ushort4 r5 = *(const ushort4*)(H + (size_t)s1.y * HID + (qlane << 2));
            ushort4 r6 = *(const ushort4*)(H + (size_t)s1.z * HID + (qlane << 2));
            ushort4 r7 = *(const ushort4*)(H + (size_t)s1.w * HID + (qlane << 2));
            acc.x += p0.x*bf2f(r0.x) + p0.y*bf2f(r1.x) + p0.z*bf2f(r2.x) + p0.w*bf2f(r3.x)
                   + p1.x*bf2f(r4.x) + p1.y*bf2f(r5.x) + p1.z*bf2f(r6.x) + p1.w*bf2f(r7.x);
            acc.y += p0.x*bf2f(r0.y) + p0.y*bf2f(r1.y) + p0.z*bf2f(r2.y) + p0.w*bf2f(r3.y)
                   + p1.x*bf2f(r4.y) + p1.y*bf2f(r5.y) + p1.z*bf2f(r6.y) + p1.w*bf2f(r7.y);
            acc.z += p0.x*bf2f(r0.z) + p0.y*bf2f(r1.z) + p0.z*bf2f(r2.z) + p0.w*bf2f(r3.z)
                   + p1.x*bf2f(r4.z) + p1.y*bf2f(r5.z) + p1.z*bf2f(r6.z) + p1.w*bf2f(r7.z);
            acc.w += p0.x*bf2f(r0.w) + p0.y*bf2f(r1.w) + p0.z*bf2f(r2.w) + p0.w*bf2f(r3.w)
                   + p1.x*bf2f(r4.w) + p1.y*bf2f(r5.w) + p1.z*bf2f(r6.w) + p1.w*bf2f(r7.w);
        }
        for (int i = 0; i < novf; ++i) {
            uint2 o = ovf[i];
            if ((int)o.x == n) {
                unsigned e = o.y;
                int s = e & 0xFFFF;
                float a = Asrc[s] + ad + c * bf2f((unsigned short)(e >> 16));
                a = (a > 0.f) ? a : NEG * a;
                float p = __expf(a);
                if (qlane == 0) lsum += p;
                ushort4 r = *(const ushort4*)(H + (size_t)s * HID + (qlane << 2));
                acc.x += p * bf2f(r.x); acc.y += p * bf2f(r.y);
                acc.z += p * bf2f(r.z); acc.w += p * bf2f(r.w);
            }
        }
        if (qlane == 0) lsum += p_self;
        #pragma unroll
        for (int o = 1; o < 16; o <<= 1) lsum += __shfl_xor(lsum, o, 64);
        denom = lsum;
    }

    {
        ushort4 r = *(const ushort4*)(H + (size_t)n * HID + (qlane << 2));
        acc.x += p_self * bf2f(r.x); acc.y += p_self * bf2f(r.y);
        acc.z += p_self * bf2f(r.z); acc.w += p_self * bf2f(r.w);
    }

    float inv = 1.f / (denom + 1e-16f);
    float4 b4 = *(const float4*)(bias + (qlane << 2));
    acc.x = acc.x * inv + b4.x;
    acc.y = acc.y * inv + b4.y;
    acc.z = acc.z * inv + b4.z;
    acc.w = acc.w * inv + b4.w;
    if (do_relu) {
        acc.x = fmaxf(acc.x, 0.f); acc.y = fmaxf(acc.y, 0.f);
        acc.z = fmaxf(acc.z, 0.f); acc.w = fmaxf(acc.w, 0.f);
    }
    *(float4*)(Out + (size_t)n * HID + (qlane << 2)) = acc;
}

// ---- fused mean pool + readout: one wave per group, binary search on sorted batch ----
__global__ __launch_bounds__(256) void pool_readout_k(
        const float* __restrict__ act, const int* __restrict__ batch,
        const float* __restrict__ lin_w, const float* __restrict__ lin_b,
        float* __restrict__ out) {
    int wv = threadIdx.x >> 6, lane = threadIdx.x & 63;
    int g = blockIdx.x * 4 + wv;
    if (g >= NG) return;
    // lower_bound(batch, g) and lower_bound(batch, g+1) — wave-uniform
    int lo = 0, hi = N_NODES;
    while (lo < hi) { int m = (lo + hi) >> 1; if (batch[m] < g) lo = m + 1; else hi = m; }
    int start = lo;
    hi = N_NODES;
    while (lo < hi) { int m = (lo + hi) >> 1; if (batch[m] < g + 1) lo = m + 1; else hi = m; }
    int end = lo;
    float acc = 0.f;
    int n = start;
    for (; n + 4 <= end; n += 4) {
        float v0 = act[(size_t)n * HID + lane];
        float v1 = act[(size_t)(n + 1) * HID + lane];
        float v2 = act[(size_t)(n + 2) * HID + lane];
        float v3 = act[(size_t)(n + 3) * HID + lane];
        acc += v0 + v1 + v2 + v3;
    }
    for (; n < end; ++n) acc += act[(size_t)n * HID + lane];
    float cntf = (float)(end - start);
    float v = acc / fmaxf(cntf, 1.f) * lin_w[lane];
    v = wave_sum(v);
    if (lane == 0) {
        float z = v + lin_b[0];
        out[g] = 1.f / (1.f + __expf(-z));
    }
}

extern "C" void kernel_launch(void* const* d_in, const int* in_sizes, int n_in,
                              void* d_out, int out_size, void* d_ws, size_t ws_size,
                              hipStream_t stream) {
    const float* x     = (const float*)d_in[0];
    const int*   ei    = (const int*)d_in[1];
    const float* ew    = (const float*)d_in[2];
    const int*   batch = (const int*)d_in[3];
    const float* W1  = (const float*)d_in[4];
    const float* as1 = (const float*)d_in[5];
    const float* ad1 = (const float*)d_in[6];
    const float* We1 = (const float*)d_in[7];
    const float* ae1 = (const float*)d_in[8];
    const float* b1  = (const float*)d_in[9];
    const float* W2  = (const float*)d_in[10];
    const float* as2 = (const float*)d_in[11];
    const float* ad2 = (const float*)d_in[12];
    const float* We2 = (const float*)d_in[13];
    const float* ae2 = (const float*)d_in[14];
    const float* b2  = (const float*)d_in[15];
    const float* W3  = (const float*)d_in[16];
    const float* as3 = (const float*)d_in[17];
    const float* ad3 = (const float*)d_in[18];
    const float* We3 = (const float*)d_in[19];
    const float* ae3 = (const float*)d_in[20];
    const float* b3  = (const float*)d_in[21];
    const float* lin_w = (const float*)d_in[22];
    const float* lin_b = (const float*)d_in[23];
    float* out = (float*)d_out;

    char* w = (char*)d_ws;
    size_t off = 0;
    auto alloc = [&](size_t bytes) -> void* {
        void* p = w + off;
        off = (off + bytes + 255) & ~(size_t)255;
        return p;
    };
    // zeroed region (memset each call; ws is poisoned)
    int*   deg      = (int*)alloc(N_NODES * sizeof(int));
    float* mean_acc = (float*)alloc(sizeof(float));
    int*   ovf_cnt  = (int*)alloc(sizeof(int));
    size_t zero_bytes = off;
    // non-zeroed
    float* ce      = (float*)alloc(4 * sizeof(float));
    unsigned* bucket = (unsigned*)alloc((size_t)N_NODES * CAP * sizeof(unsigned));
    uint2* ovf     = (uint2*)alloc((size_t)N_EDGES * sizeof(uint2));
    float* a_src   = (float*)alloc(N_NODES * sizeof(float));
    float* a_dst   = (float*)alloc(N_NODES * sizeof(float));
    unsigned short* hbuf = (unsigned short*)alloc((size_t)N_NODES * HID * sizeof(unsigned short));
    float* actA    = (float*)alloc((size_t)N_NODES * HID * sizeof(float));
    float* actB    = (float*)alloc((size_t)N_NODES * HID * sizeof(float));

    hipMemsetAsync(d_ws, 0, zero_bytes, stream);

    int xgrid = ((N_EDGES + EPB - 1) / EPB) * 8;
    scatter_all_k<<<xgrid, 256, 0, stream>>>(ei, ew, deg, bucket, ovf, ovf_cnt,
                                             mean_acc, We1, ae1, We2, ae2, We3, ae3, ce);

    int ggrid = (N_NODES + 63) / 64;
    int agrid = (N_NODES + 15) / 16;

    size_t lds1 = (size_t)(F_IN_DIM * HID + 64 * 17) * sizeof(float);
    size_t lds2 = (size_t)(HID * HID + 64 * 17) * sizeof(float);

    // layer 1
    gemm_att_k<<<ggrid, 256, lds1, stream>>>(x, F_IN_DIM, W1, as1, ad1, hbuf, a_src, a_dst);
    aggregate_k<<<agrid, 256, 0, stream>>>(hbuf, deg, bucket, ovf, ovf_cnt,
                                           a_src, a_dst, ce, 0, mean_acc, b1, actA, 1);
    // layer 2
    gemm_att_k<<<ggrid, 256, lds2, stream>>>(actA, HID, W2, as2, ad2, hbuf, a_src, a_dst);
    aggregate_k<<<agrid, 256, 0, stream>>>(hbuf, deg, bucket, ovf, ovf_cnt,
                                           a_src, a_dst, ce, 1, mean_acc, b2, actB, 1);
    // layer 3
    gemm_att_k<<<ggrid, 256, lds2, stream>>>(actB, HID, W3, as3, ad3, hbuf, a_src, a_dst);
    aggregate_k<<<agrid, 256, 0, stream>>>(hbuf, deg, bucket, ovf, ovf_cnt,
                                           a_src, a_dst, ce, 2, mean_acc, b3, actA, 0);

    // fused pool + readout
    pool_readout_k<<<NG / 4, 256, 0, stream>>>(actA, batch, lin_w, lin_b, out);
}

// Round 11
// 280.666 us; speedup vs baseline: 1.0193x; 1.0193x over previous
//
#include <hip/hip_runtime.h>
#include <math.h>

#define N_NODES 50000
#define N_EDGES 800000
#define F_IN_DIM 128
#define HID 64
#define NG 512
#define NEG 0.2f
#define SLICE ((N_NODES + 7) / 8)   // 6250 nodes per XCD slice
#define EPB 2048                     // edges per 8-block group
#define CAP 64                       // bucket capacity per node
#define XGRID (((N_EDGES + EPB - 1) / EPB) * 8)   // 3128 scatter blocks
#define GGRID ((N_NODES + 63) / 64)               // 782 gemm blocks

static __device__ __forceinline__ float wave_sum(float v) {
    for (int o = 32; o; o >>= 1) v += __shfl_xor(v, o, 64);
    return v;
}

// bf16 pack/unpack (RNE)
static __device__ __forceinline__ unsigned short f2bf(float f) {
    union { float f; unsigned u; } v; v.f = f;
    unsigned r = (v.u + 0x7FFF + ((v.u >> 16) & 1)) >> 16;
    return (unsigned short)r;
}
static __device__ __forceinline__ float bf2f(unsigned short b) {
    union { unsigned u; float f; } v; v.u = ((unsigned)b) << 16;
    return v.f;
}

// ---- FUSED: bucket build (blocks 0..XGRID) + layer-1 GEMM (blocks XGRID..) ----
// Independent work co-resident in one launch: scatter is latency-bound,
// gemm is VALU-bound. Gemm stages W in 16x64 tiles (8.4KB LDS total).
__global__ __launch_bounds__(256) void scatter_gemm1_k(
        const int* __restrict__ ei, const float* __restrict__ ew,
        int* __restrict__ deg, unsigned* __restrict__ bucket,
        uint2* __restrict__ ovf, int* __restrict__ ovf_cnt,
        float* __restrict__ mean_acc,
        const float* __restrict__ We1, const float* __restrict__ ae1,
        const float* __restrict__ We2, const float* __restrict__ ae2,
        const float* __restrict__ We3, const float* __restrict__ ae3,
        float* __restrict__ ce,
        const float* __restrict__ X, const float* __restrict__ W,
        const float* __restrict__ as_, const float* __restrict__ ad_,
        unsigned short* __restrict__ H, float* __restrict__ Asrc,
        float* __restrict__ Adst) {
    extern __shared__ float smem[];
    const int tid = threadIdx.x;

    if (blockIdx.x < XGRID) {
        // ---------------- scatter path ----------------
        int grp = blockIdx.x >> 3, slice = blockIdx.x & 7;
        int lo = slice * SLICE, hi = lo + SLICE;
        int base = grp * EPB;
        int lim = min(base + EPB, N_EDGES);
        float s = 0.f;
        for (int e = base + tid; e < lim; e += 256) {
            int dst = ei[N_EDGES + e];
            if (slice == 0) s += ew[e];
            if (dst >= lo && dst < hi) {
                int src = ei[e];
                float w = ew[e];
                int pos = atomicAdd(&deg[dst], 1);
                unsigned entry = (unsigned)(src & 0xFFFF) | ((unsigned)f2bf(w) << 16);
                if (pos < CAP) bucket[(dst << 6) + pos] = entry;
                else { int op = atomicAdd(ovf_cnt, 1); ovf[op] = make_uint2((unsigned)dst, entry); }
            }
        }
        int lane = tid & 63, wv = tid >> 6;
        if (slice == 0) {
            s = wave_sum(s);
            if (lane == 0) smem[wv] = s;
            __syncthreads();
            if (tid == 0) atomicAdd(mean_acc, smem[0] + smem[1] + smem[2] + smem[3]);
        }
        if (blockIdx.x == 0 && wv >= 1) {
            const float* We = (wv == 1) ? We1 : (wv == 2) ? We2 : We3;
            const float* ae = (wv == 1) ? ae1 : (wv == 2) ? ae2 : ae3;
            float v = We[lane] * ae[lane];
            v = wave_sum(v);
            if (lane == 0) ce[wv - 1] = v;
        }
        return;
    }

    // ---------------- gemm path (layer 1, F = 128) ----------------
    float* Xs = smem;              // 64*17 floats
    float* Wt = smem + 64 * 17;    // 16*64 floats (current k-tile)
    const int tx = tid & 15, ty = tid >> 4;
    const int bid = blockIdx.x - XGRID;
    const int rowBase = bid * 64;

    float4 acc0 = {0,0,0,0}, acc1 = {0,0,0,0}, acc2 = {0,0,0,0}, acc3 = {0,0,0,0};
    const int xrow = tid >> 2;
    const int xkq  = tid & 3;
    const float4* W4 = (const float4*)W;
    float4* Wt4 = (float4*)Wt;

    #pragma unroll 2
    for (int kt = 0; kt < (F_IN_DIM >> 4); ++kt) {
        __syncthreads();
        int k0 = kt << 4;
        int grow = rowBase + xrow;
        float4 xv = {0,0,0,0};
        if (grow < N_NODES)
            xv = *(const float4*)(X + (size_t)grow * F_IN_DIM + k0 + (xkq << 2));
        float* xd = Xs + xrow * 17 + (xkq << 2);
        xd[0] = xv.x; xd[1] = xv.y; xd[2] = xv.z; xd[3] = xv.w;
        Wt4[tid] = W4[(kt << 8) + tid];   // 16x64 tile, one float4/thread
        __syncthreads();

        #pragma unroll
        for (int kk = 0; kk < 16; ++kk) {
            float4 b = *(const float4*)&Wt[kk * HID + (tx << 2)];
            float a0 = Xs[(ty * 4 + 0) * 17 + kk];
            float a1 = Xs[(ty * 4 + 1) * 17 + kk];
            float a2 = Xs[(ty * 4 + 2) * 17 + kk];
            float a3 = Xs[(ty * 4 + 3) * 17 + kk];
            acc0.x += a0 * b.x; acc0.y += a0 * b.y; acc0.z += a0 * b.z; acc0.w += a0 * b.w;
            acc1.x += a1 * b.x; acc1.y += a1 * b.y; acc1.z += a1 * b.z; acc1.w += a1 * b.w;
            acc2.x += a2 * b.x; acc2.y += a2 * b.y; acc2.z += a2 * b.z; acc2.w += a2 * b.w;
            acc3.x += a3 * b.x; acc3.y += a3 * b.y; acc3.z += a3 * b.z; acc3.w += a3 * b.w;
        }
    }

    float4 as4 = *(const float4*)(as_ + (tx << 2));
    float4 ad4 = *(const float4*)(ad_ + (tx << 2));
    float4 accs[4] = {acc0, acc1, acc2, acc3};
    #pragma unroll
    for (int i = 0; i < 4; ++i) {
        int row = rowBase + ty * 4 + i;
        if (row >= N_NODES) break;
        float4 a = accs[i];
        ushort4 hv;
        hv.x = f2bf(a.x); hv.y = f2bf(a.y); hv.z = f2bf(a.z); hv.w = f2bf(a.w);
        *(ushort4*)(H + (size_t)row * HID + (tx << 2)) = hv;
        float vs = a.x * as4.x + a.y * as4.y + a.z * as4.z + a.w * as4.w;
        float vd = a.x * ad4.x + a.y * ad4.y + a.z * ad4.z + a.w * ad4.w;
        #pragma unroll
        for (int o = 8; o; o >>= 1) { vs += __shfl_xor(vs, o, 64); vd += __shfl_xor(vd, o, 64); }
        if (tx == 0) { Asrc[row] = vs; Adst[row] = vd; }
    }
}

// ---- H = X @ W (register-tiled), H stored bf16, fused a_src/a_dst (layers 2/3) ----
__global__ __launch_bounds__(256) void gemm_att_k(
        const float* __restrict__ X, int F,
        const float* __restrict__ W,
        const float* __restrict__ as_, const float* __restrict__ ad_,
        unsigned short* __restrict__ H, float* __restrict__ Asrc,
        float* __restrict__ Adst) {
    extern __shared__ float smem[];
    float* Ws = smem;               // F*64 floats
    float* Xs = smem + F * HID;     // 64*17 floats
    const int tid = threadIdx.x;
    const int tx = tid & 15, ty = tid >> 4;
    const int rowBase = blockIdx.x * 64;

    {
        const float4* W4 = (const float4*)W;
        float4* Ws4 = (float4*)Ws;
        int n4 = (F * HID) >> 2;
        for (int i = tid; i < n4; i += 256) Ws4[i] = W4[i];
    }

    float4 acc0 = {0,0,0,0}, acc1 = {0,0,0,0}, acc2 = {0,0,0,0}, acc3 = {0,0,0,0};

    const int xrow = tid >> 2;
    const int xkq  = tid & 3;
    const int nkt = F >> 4;

    for (int kt = 0; kt < nkt; ++kt) {
        __syncthreads();
        int k0 = kt << 4;
        int grow = rowBase + xrow;
        float4 xv = {0,0,0,0};
        if (grow < N_NODES)
            xv = *(const float4*)(X + (size_t)grow * F + k0 + (xkq << 2));
        float* xd = Xs + xrow * 17 + (xkq << 2);
        xd[0] = xv.x; xd[1] = xv.y; xd[2] = xv.z; xd[3] = xv.w;
        __syncthreads();

        #pragma unroll
        for (int kk = 0; kk < 16; ++kk) {
            float4 b = *(const float4*)&Ws[(k0 + kk) * HID + (tx << 2)];
            float a0 = Xs[(ty * 4 + 0) * 17 + kk];
            float a1 = Xs[(ty * 4 + 1) * 17 + kk];
            float a2 = Xs[(ty * 4 + 2) * 17 + kk];
            float a3 = Xs[(ty * 4 + 3) * 17 + kk];
            acc0.x += a0 * b.x; acc0.y += a0 * b.y; acc0.z += a0 * b.z; acc0.w += a0 * b.w;
            acc1.x += a1 * b.x; acc1.y += a1 * b.y; acc1.z += a1 * b.z; acc1.w += a1 * b.w;
            acc2.x += a2 * b.x; acc2.y += a2 * b.y; acc2.z += a2 * b.z; acc2.w += a2 * b.w;
            acc3.x += a3 * b.x; acc3.y += a3 * b.y; acc3.z += a3 * b.z; acc3.w += a3 * b.w;
        }
    }

    float4 as4 = *(const float4*)(as_ + (tx << 2));
    float4 ad4 = *(const float4*)(ad_ + (tx << 2));
    float4 accs[4] = {acc0, acc1, acc2, acc3};
    #pragma unroll
    for (int i = 0; i < 4; ++i) {
        int row = rowBase + ty * 4 + i;
        if (row >= N_NODES) break;
        float4 a = accs[i];
        ushort4 hv;
        hv.x = f2bf(a.x); hv.y = f2bf(a.y); hv.z = f2bf(a.z); hv.w = f2bf(a.w);
        *(ushort4*)(H + (size_t)row * HID + (tx << 2)) = hv;
        float vs = a.x * as4.x + a.y * as4.y + a.z * as4.z + a.w * as4.w;
        float vd = a.x * ad4.x + a.y * ad4.y + a.z * ad4.z + a.w * ad4.w;
        #pragma unroll
        for (int o = 8; o; o >>= 1) { vs += __shfl_xor(vs, o, 64); vd += __shfl_xor(vd, o, 64); }
        if (tx == 0) { Asrc[row] = vs; Adst[row] = vd; }
    }
}

// ---- per-dst-node softmax + weighted gather (bucket layout, self-loop inline) ----
__global__ __launch_bounds__(256) void aggregate_k(
        const unsigned short* __restrict__ H, const int* __restrict__ degArr,
        const unsigned* __restrict__ bucket,
        const uint2* __restrict__ ovf, const int* __restrict__ ovf_cnt_p,
        const float* __restrict__ Asrc, const float* __restrict__ Adst,
        const float* __restrict__ ceArr, int ci,
        const float* __restrict__ mean_acc,
        const float* __restrict__ bias, float* __restrict__ Out,
        int do_relu) {
    __shared__ float lp[16][64];
    __shared__ int   ls[16][64];
    int wv = threadIdx.x >> 6, lane = threadIdx.x & 63;
    int qid = lane >> 4, qlane = lane & 15;
    int slot = wv * 4 + qid;
    int n = blockIdx.x * 16 + slot;
    if (n >= N_NODES) return;
    int deg = degArr[n];
    int start = n << 6;
    float c = ceArr[ci];
    float ad = Adst[n];
    float mv = mean_acc[0] * (1.0f / (float)N_EDGES);
    float4 acc = {0, 0, 0, 0};
    float denom;

    float a_self = Asrc[n] + ad + c * mv;
    a_self = (a_self > 0.f) ? a_self : NEG * a_self;
    float p_self = __expf(a_self);

    if (deg <= CAP) {
        float lsum = 0.f;
        #pragma unroll
        for (int t = 0; t < 4; ++t) {
            int j = qlane + (t << 4);
            float p = 0.f; int s = 0;
            if (j < deg) {
                unsigned e = bucket[start + j];
                s = e & 0xFFFF;
                float a = Asrc[s] + ad + c * bf2f((unsigned short)(e >> 16));
                a = (a > 0.f) ? a : NEG * a;
                p = __expf(a);
                lsum += p;
            }
            lp[slot][j] = p;
            ls[slot][j] = s;
        }
        if (qlane == 0) lsum += p_self;
        #pragma unroll
        for (int o = 1; o < 16; o <<= 1) lsum += __shfl_xor(lsum, o, 64);
        denom = lsum;
        __builtin_amdgcn_wave_barrier();
        int dpad = (deg + 7) & ~7;
        for (int j = 0; j < dpad; j += 8) {
            float4 p0 = *(float4*)&lp[slot][j];
            float4 p1 = *(float4*)&lp[slot][j + 4];
            int4 s0 = *(int4*)&ls[slot][j];
            int4 s1 = *(int4*)&ls[slot][j + 4];
            ushort4 r0 = *(const ushort4*)(H + (size_t)s0.x * HID + (qlane << 2));
            ushort4 r1 = *(const ushort4*)(H + (size_t)s0.y * HID + (qlane << 2));
            ushort4 r2 = *(const ushort4*)(H + (size_t)s0.z * HID + (qlane << 2));
            ushort4 r3 = *(const ushort4*)(H + (size_t)s0.w * HID + (qlane << 2));
            ushort4 r4 = *(const ushort4*)(H + (size_t)s1.x * HID + (qlane << 2));
            ushort4 r5 = *(const ushort4*)(H + (size_t)s1.y * HID + (qlane << 2));
            ushort4 r6 = *(const ushort4*)(H + (size_t)s1.z * HID + (qlane << 2));
            ushort4 r7 = *(const ushort4*)(H + (size_t)s1.w * HID + (qlane << 2));
            acc.x += p0.x*bf2f(r0.x) + p0.y*bf2f(r1.x) + p0.z*bf2f(r2.x) + p0.w*bf2f(r3.x)
                   + p1.x*bf2f(r4.x) + p1.y*bf2f(r5.x) + p1.z*bf2f(r6.x) + p1.w*bf2f(r7.x);
            acc.y += p0.x*bf2f(r0.y) + p0.y*bf2f(r1.y) + p0.z*bf2f(r2.y) + p0.w*bf2f(r3.y)
                   + p1.x*bf2f(r4.y) + p1.y*bf2f(r5.y) + p1.z*bf2f(r6.y) + p1.w*bf2f(r7.y);
            acc.z += p0.x*bf2f(r0.z) + p0.y*bf2f(r1.z) + p0.z*bf2f(r2.z) + p0.w*bf2f(r3.z)
                   + p1.x*bf2f(r4.z) + p1.y*bf2f(r5.z) + p1.z*bf2f(r6.z) + p1.w*bf2f(r7.z);
            acc.w += p0.x*bf2f(r0.w) + p0.y*bf2f(r1.w) + p0.z*bf2f(r2.w) + p0.w*bf2f(r3.w)
                   + p1.x*bf2f(r4.w) + p1.y*bf2f(r5.w) + p1.z*bf2f(r6.w) + p1.w*bf2f(r7.w);
        }
    } else {
        int novf = *ovf_cnt_p;
        float lsum = 0.f;
        #pragma unroll
        for (int t = 0; t < 4; ++t) {
            int j = qlane + (t << 4);
            unsigned e = bucket[start + j];
            int s = e & 0xFFFF;
            float a = Asrc[s] + ad + c * bf2f((unsigned short)(e >> 16));
            a = (a > 0.f) ? a : NEG * a;
            float p = __expf(a);
            lsum += p;
            lp[slot][j] = p;
            ls[slot][j] = s;
        }
        __builtin_amdgcn_wave_barrier();
        for (int j = 0; j < 64; j += 8) {
            float4 p0 = *(float4*)&lp[slot][j];
            float4 p1 = *(float4*)&lp[slot][j + 4];
            int4 s0 = *(int4*)&ls[slot][j];
            int4 s1 = *(int4*)&ls[slot][j + 4];
            ushort4 r0 = *(const ushort4*)(H + (size_t)s0.x * HID + (qlane << 2));
            ushort4 r1 = *(const ushort4*)(H + (size_t)s0.y * HID + (qlane << 2));
            ushort4 r2 = *(const ushort4*)(H + (size_t)s0.z * HID + (qlane << 2));
            ushort4 r3 = *(const ushort4*)(H + (size_t)s0.w * HID + (qlane << 2));
            ushort4 r4 = *(const ushort4*)(H + (size_t)s1.x * HID + (qlane << 2));
            ushort4 r5 = *(const ushort4*)(H + (size_t)s1.y * HID + (qlane << 2));
            ushort4 r6 = *(const ushort4*)(H + (size_t)s1.z * HID + (qlane << 2));
            ushort4 r7 = *(const ushort4*)(H + (size_t)s1.w * HID + (qlane << 2));
            acc.x += p0.x*bf2f(r0.x) + p0.y*bf2f(r1.x) + p0.z*bf2f(r2.x) + p0.w*bf2f(r3.x)
                   + p1.x*bf2f(r4.x) + p1.y*bf2f(r5.x) + p1.z*bf2f(r6.x) + p1.w*bf2f(r7.x);
            acc.y += p0.x*bf2f(r0.y) + p0.y*bf2f(r1.y) + p0.z*bf2f(r2.y) + p0.w*bf2f(r3.y)
                   + p1.x*bf2f(r4.y) + p1.y*bf2f(r5.y) + p1.z*bf2f(r6.y) + p1.w*bf2f(r7.y);
            acc.z += p0.x*bf2f(r0.z) + p0.y*bf2f(r1.z) + p0.z*bf2f(r2.z) + p0.w*bf2f(r3.z)
                   + p1.x*bf2f(r4.z) + p1.y*bf2f(r5.z) + p1.z*bf2f(r6.z) + p1.w*bf2f(r7.z);
            acc.w += p0.x*bf2f(r0.w) + p0.y*bf2f(r1.w) + p0.z*bf2f(r2.w) + p0.w*bf2f(r3.w)
                   + p1.x*bf2f(r4.w) + p1.y*bf2f(r5.w) + p1.z*bf2f(r6.w) + p1.w*bf2f(r7.w);
        }
        for (int i = 0; i < novf; ++i) {
            uint2 o = ovf[i];
            if ((int)o.x == n) {
                unsigned e = o.y;
                int s = e & 0xFFFF;
                float a = Asrc[s] + ad + c * bf2f((unsigned short)(e >> 16));
                a = (a > 0.f) ? a : NEG * a;
                float p = __expf(a);
                if (qlane == 0) lsum += p;
                ushort4 r = *(const ushort4*)(H + (size_t)s * HID + (qlane << 2));
                acc.x += p * bf2f(r.x); acc.y += p * bf2f(r.y);
                acc.z += p * bf2f(r.z); acc.w += p * bf2f(r.w);
            }
        }
        if (qlane == 0) lsum += p_self;
        #pragma unroll
        for (int o = 1; o < 16; o <<= 1) lsum += __shfl_xor(lsum, o, 64);
        denom = lsum;
    }

    {
        ushort4 r = *(const ushort4*)(H + (size_t)n * HID + (qlane << 2));
        acc.x += p_self * bf2f(r.x); acc.y += p_self * bf2f(r.y);
        acc.z += p_self * bf2f(r.z); acc.w += p_self * bf2f(r.w);
    }

    float inv = 1.f / (denom + 1e-16f);
    float4 b4 = *(const float4*)(bias + (qlane << 2));
    acc.x = acc.x * inv + b4.x;
    acc.y = acc.y * inv + b4.y;
    acc.z = acc.z * inv + b4.z;
    acc.w = acc.w * inv + b4.w;
    if (do_relu) {
        acc.x = fmaxf(acc.x, 0.f); acc.y = fmaxf(acc.y, 0.f);
        acc.z = fmaxf(acc.z, 0.f); acc.w = fmaxf(acc.w, 0.f);
    }
    *(float4*)(Out + (size_t)n * HID + (qlane << 2)) = acc;
}

// ---- fused mean pool + readout: one wave per group, binary search on sorted batch ----
__global__ __launch_bounds__(256) void pool_readout_k(
        const float* __restrict__ act, const int* __restrict__ batch,
        const float* __restrict__ lin_w, const float* __restrict__ lin_b,
        float* __restrict__ out) {
    int wv = threadIdx.x >> 6, lane = threadIdx.x & 63;
    int g = blockIdx.x * 4 + wv;
    if (g >= NG) return;
    int lo = 0, hi = N_NODES;
    while (lo < hi) { int m = (lo + hi) >> 1; if (batch[m] < g) lo = m + 1; else hi = m; }
    int start = lo;
    hi = N_NODES;
    while (lo < hi) { int m = (lo + hi) >> 1; if (batch[m] < g + 1) lo = m + 1; else hi = m; }
    int end = lo;
    float acc = 0.f;
    int n = start;
    for (; n + 4 <= end; n += 4) {
        float v0 = act[(size_t)n * HID + lane];
        float v1 = act[(size_t)(n + 1) * HID + lane];
        float v2 = act[(size_t)(n + 2) * HID + lane];
        float v3 = act[(size_t)(n + 3) * HID + lane];
        acc += v0 + v1 + v2 + v3;
    }
    for (; n < end; ++n) acc += act[(size_t)n * HID + lane];
    float cntf = (float)(end - start);
    float v = acc / fmaxf(cntf, 1.f) * lin_w[lane];
    v = wave_sum(v);
    if (lane == 0) {
        float z = v + lin_b[0];
        out[g] = 1.f / (1.f + __expf(-z));
    }
}

extern "C" void kernel_launch(void* const* d_in, const int* in_sizes, int n_in,
                              void* d_out, int out_size, void* d_ws, size_t ws_size,
                              hipStream_t stream) {
    const float* x     = (const float*)d_in[0];
    const int*   ei    = (const int*)d_in[1];
    const float* ew    = (const float*)d_in[2];
    const int*   batch = (const int*)d_in[3];
    const float* W1  = (const float*)d_in[4];
    const float* as1 = (const float*)d_in[5];
    const float* ad1 = (const float*)d_in[6];
    const float* We1 = (const float*)d_in[7];
    const float* ae1 = (const float*)d_in[8];
    const float* b1  = (const float*)d_in[9];
    const float* W2  = (const float*)d_in[10];
    const float* as2 = (const float*)d_in[11];
    const float* ad2 = (const float*)d_in[12];
    const float* We2 = (const float*)d_in[13];
    const float* ae2 = (const float*)d_in[14];
    const float* b2  = (const float*)d_in[15];
    const float* W3  = (const float*)d_in[16];
    const float* as3 = (const float*)d_in[17];
    const float* ad3 = (const float*)d_in[18];
    const float* We3 = (const float*)d_in[19];
    const float* ae3 = (const float*)d_in[20];
    const float* b3  = (const float*)d_in[21];
    const float* lin_w = (const float*)d_in[22];
    const float* lin_b = (const float*)d_in[23];
    float* out = (float*)d_out;

    char* w = (char*)d_ws;
    size_t off = 0;
    auto alloc = [&](size_t bytes) -> void* {
        void* p = w + off;
        off = (off + bytes + 255) & ~(size_t)255;
        return p;
    };
    // zeroed region (memset each call; ws is poisoned)
    int*   deg      = (int*)alloc(N_NODES * sizeof(int));
    float* mean_acc = (float*)alloc(sizeof(float));
    int*   ovf_cnt  = (int*)alloc(sizeof(int));
    size_t zero_bytes = off;
    // non-zeroed
    float* ce      = (float*)alloc(4 * sizeof(float));
    unsigned* bucket = (unsigned*)alloc((size_t)N_NODES * CAP * sizeof(unsigned));
    uint2* ovf     = (uint2*)alloc((size_t)N_EDGES * sizeof(uint2));
    float* a_src   = (float*)alloc(N_NODES * sizeof(float));
    float* a_dst   = (float*)alloc(N_NODES * sizeof(float));
    unsigned short* hbuf = (unsigned short*)alloc((size_t)N_NODES * HID * sizeof(unsigned short));
    float* actA    = (float*)alloc((size_t)N_NODES * HID * sizeof(float));
    float* actB    = (float*)alloc((size_t)N_NODES * HID * sizeof(float));

    hipMemsetAsync(d_ws, 0, zero_bytes, stream);

    int agrid = (N_NODES + 15) / 16;
    size_t lds_f = (size_t)(64 * 17 + 16 * 64) * sizeof(float);   // 8.4 KB
    size_t lds2  = (size_t)(HID * HID + 64 * 17) * sizeof(float);

    // fused: bucket build + layer-1 GEMM (independent work, one launch)
    scatter_gemm1_k<<<XGRID + GGRID, 256, lds_f, stream>>>(
        ei, ew, deg, bucket, ovf, ovf_cnt, mean_acc,
        We1, ae1, We2, ae2, We3, ae3, ce,
        x, W1, as1, ad1, hbuf, a_src, a_dst);

    aggregate_k<<<agrid, 256, 0, stream>>>(hbuf, deg, bucket, ovf, ovf_cnt,
                                           a_src, a_dst, ce, 0, mean_acc, b1, actA, 1);
    // layer 2
    gemm_att_k<<<GGRID, 256, lds2, stream>>>(actA, HID, W2, as2, ad2, hbuf, a_src, a_dst);
    aggregate_k<<<agrid, 256, 0, stream>>>(hbuf, deg, bucket, ovf, ovf_cnt,
                                           a_src, a_dst, ce, 1, mean_acc, b2, actB, 1);
    // layer 3
    gemm_att_k<<<GGRID, 256, lds2, stream>>>(actB, HID, W3, as3, ad3, hbuf, a_src, a_dst);
    aggregate_k<<<agrid, 256, 0, stream>>>(hbuf, deg, bucket, ovf, ovf_cnt,
                                           a_src, a_dst, ce, 2, mean_acc, b3, actA, 0);

    // fused pool + readout
    pool_readout_k<<<NG / 4, 256, 0, stream>>>(actA, batch, lin_w, lin_b, out);
}